// Round 3
// baseline (686.162 us; speedup 1.0000x reference)
//
#include <hip/hip_runtime.h>

#define DEVI static __device__ __forceinline__

namespace {

constexpr int NV   = 120000;
constexpr int ND   = 30000;
constexpr int NV2  = 60000;
constexpr int NPTS = 400000;
constexpr int C    = 128;

DEVI float lrelu(float x){ return x > 0.f ? x : 0.1f*x; }

// ======== sort machinery: histogram -> scan -> order-scatter ========

__global__ void k_hist(const int* __restrict__ seg, int n, int* __restrict__ hist){
  int i = blockIdx.x * blockDim.x + threadIdx.x;
  if (i < n) atomicAdd(&hist[seg[i]], 1);
}

// single-block exclusive scan of hist[N] -> off[N+1], plus a mutable copy in next[N]
__global__ __launch_bounds__(1024) void k_scan(const int* __restrict__ hist,
                                               int* __restrict__ off,
                                               int* __restrict__ next, int N){
  __shared__ int ls[1024];
  int t = threadIdx.x;
  int chunk = (N + 1023) >> 10;
  int b = t * chunk, e = min(b + chunk, N);
  int s = 0;
  for (int i = b; i < e; ++i) s += hist[i];
  ls[t] = s;
  __syncthreads();
  for (int d = 1; d < 1024; d <<= 1){
    int v = (t >= d) ? ls[t - d] : 0;
    __syncthreads();
    ls[t] += v;
    __syncthreads();
  }
  int run = (t == 0) ? 0 : ls[t - 1];
  for (int i = b; i < e; ++i){
    off[i] = run; next[i] = run;
    run += hist[i];
  }
  if (b < N && e == N) off[N] = run;
}

// points: record point id and its source voxel per segment slot
__global__ void k_order_p(const int* __restrict__ cin, const int* __restrict__ cil,
                          int* __restrict__ next, int* __restrict__ pid,
                          int* __restrict__ vsrc){
  int p = blockIdx.x * blockDim.x + threadIdx.x;
  if (p < NPTS){
    int s = cin[p];
    int idx = atomicAdd(&next[s], 1);
    pid[idx]  = p;
    vsrc[idx] = cil[p];
  }
}

// voxels: record voxel id per downsample-segment slot
__global__ void k_order_ds(const int* __restrict__ inv, int* __restrict__ next,
                           int* __restrict__ vid){
  int v = blockIdx.x * blockDim.x + threadIdx.x;
  if (v < NV){
    int d = inv[v];
    int idx = atomicAdd(&next[d], 1);
    vid[idx] = v;
  }
}

// ======== segmented means (atomic-free): one wave per segment ========

// ds_mean[d] = mean over {features[v]+v_fea[v] : inv[v]=d}; zero if empty
__global__ __launch_bounds__(256) void k_segmean_ds(
    const float* __restrict__ f, const float* __restrict__ vf,
    const int* __restrict__ off, const int* __restrict__ vid,
    float* __restrict__ ds_mean){
  int s = blockIdx.x * 4 + (threadIdx.x >> 6);
  if (s >= ND) return;
  int lane = threadIdx.x & 63;
  int start = off[s], end = off[s + 1];
  float2 acc = make_float2(0.f, 0.f);
  for (int j = start; j < end; ++j){
    int v = vid[j];
    float2 a = *(const float2*)(f  + (size_t)v * C + lane * 2);
    float2 b = *(const float2*)(vf + (size_t)v * C + lane * 2);
    acc.x += a.x + b.x; acc.y += a.y + b.y;
  }
  float invn = 1.f / (float)max(end - start, 1);
  acc.x *= invn; acc.y *= invn;
  *(float2*)(ds_mean + (size_t)s * C + lane * 2) = acc;
}

// per next-scale segment: mean of z[vsrc[j]] rows, written directly to ALL its
// output point rows (fuses divide + final gather; p_mean never materialized)
__global__ __launch_bounds__(256) void k_segmean_p(
    const float* __restrict__ z, const int* __restrict__ off,
    const int* __restrict__ pid, const int* __restrict__ vsrc,
    float* __restrict__ out){
  int s = blockIdx.x * 4 + (threadIdx.x >> 6);
  if (s >= NV2) return;
  int lane = threadIdx.x & 63;
  int start = off[s], end = off[s + 1];
  float2 acc = make_float2(0.f, 0.f);
  for (int j = start; j < end; ++j){
    int v = vsrc[j];
    float2 a = *(const float2*)(z + (size_t)v * C + lane * 2);
    acc.x += a.x; acc.y += a.y;
  }
  float invn = 1.f / (float)max(end - start, 1);
  acc.x *= invn; acc.y *= invn;
  for (int j = start; j < end; ++j){
    int p = pid[j];
    *(float2*)(out + (size_t)p * C + lane * 2) = acc;
  }
}

// ======== generic row-tiled f32 GEMM (unchanged core) ========
template<int K, int N, bool LRELU, bool STATS, bool PRESCALE,
         bool TWOIN, bool ROWADD, bool BIAS>
__global__ __launch_bounds__(256) void k_gemm(
    const float* __restrict__ A, const float* __restrict__ A2,
    const float* __restrict__ scale, const float* __restrict__ shift,
    const float* __restrict__ W, const float* __restrict__ bias,
    const float* __restrict__ rowtab, const int* __restrict__ rowidx,
    float* __restrict__ out, float* __restrict__ stats, int M)
{
  constexpr int BM = 64;
  constexpr int G  = N / 4;
  constexpr int TY = 256 / G;
  constexpr int R  = BM / TY;
  constexpr int KV = K / 4;

  __shared__ float At[K][BM + 4];
  __shared__ int   sidx[ROWADD ? BM : 1];
  __shared__ float red[STATS ? 2 * TY * N : 1];

  const int tid  = threadIdx.x;
  const int tx   = tid % G;
  const int ty   = tid / G;
  const int row0 = blockIdx.x * BM;

  for (int i = tid; i < BM * KV; i += 256){
    int r  = i / KV;
    int kc = (i % KV) * 4;
    int row = row0 + r;
    float4 v = make_float4(0.f, 0.f, 0.f, 0.f);
    if (row < M){
      v = *(const float4*)(A + (size_t)row * K + kc);
      if constexpr (TWOIN){
        float4 w = *(const float4*)(A2 + (size_t)row * K + kc);
        v.x += w.x; v.y += w.y; v.z += w.z; v.w += w.w;
      }
      if constexpr (PRESCALE){
        v.x = v.x * scale[kc + 0] + shift[kc + 0];
        v.y = v.y * scale[kc + 1] + shift[kc + 1];
        v.z = v.z * scale[kc + 2] + shift[kc + 2];
        v.w = v.w * scale[kc + 3] + shift[kc + 3];
      }
    }
    At[kc + 0][r] = v.x; At[kc + 1][r] = v.y;
    At[kc + 2][r] = v.z; At[kc + 3][r] = v.w;
  }
  if constexpr (ROWADD){
    for (int i = tid; i < BM; i += 256){
      int row = row0 + i;
      sidx[i] = row < M ? rowidx[row] : 0;
    }
  }
  __syncthreads();

  float acc[R][4];
  #pragma unroll
  for (int r = 0; r < R; ++r)
    for (int j = 0; j < 4; ++j) acc[r][j] = 0.f;

  #pragma unroll 4
  for (int k = 0; k < K; ++k){
    float4 w4 = *(const float4*)(W + (size_t)k * N + tx * 4);
    const float4* ap = (const float4*)&At[k][ty * R];
    #pragma unroll
    for (int rq = 0; rq < R / 4; ++rq){
      float4 a4 = ap[rq];
      float av[4] = {a4.x, a4.y, a4.z, a4.w};
      #pragma unroll
      for (int rr = 0; rr < 4; ++rr){
        int r = rq * 4 + rr;
        acc[r][0] += av[rr] * w4.x;
        acc[r][1] += av[rr] * w4.y;
        acc[r][2] += av[rr] * w4.z;
        acc[r][3] += av[rr] * w4.w;
      }
    }
  }

  float bx[4] = {0.f, 0.f, 0.f, 0.f};
  if constexpr (BIAS){
    float4 b = *(const float4*)(bias + tx * 4);
    bx[0] = b.x; bx[1] = b.y; bx[2] = b.z; bx[3] = b.w;
  }

  float ps[4] = {0.f,0.f,0.f,0.f}, pq[4] = {0.f,0.f,0.f,0.f};
  #pragma unroll
  for (int r = 0; r < R; ++r){
    int row = row0 + ty * R + r;
    if (row < M){
      float o[4];
      #pragma unroll
      for (int j = 0; j < 4; ++j) o[j] = acc[r][j] + bx[j];
      if constexpr (ROWADD){
        int d = sidx[ty * R + r];
        float4 tv = *(const float4*)(rowtab + (size_t)d * N + tx * 4);
        o[0] += tv.x; o[1] += tv.y; o[2] += tv.z; o[3] += tv.w;
      }
      if constexpr (LRELU){
        #pragma unroll
        for (int j = 0; j < 4; ++j) o[j] = lrelu(o[j]);
      }
      *(float4*)(out + (size_t)row * N + tx * 4) = make_float4(o[0], o[1], o[2], o[3]);
      if constexpr (STATS){
        #pragma unroll
        for (int j = 0; j < 4; ++j){ ps[j] += o[j]; pq[j] += o[j] * o[j]; }
      }
    }
  }

  if constexpr (STATS){
    #pragma unroll
    for (int j = 0; j < 4; ++j){
      red[(0 * TY + ty) * N + tx * 4 + j] = ps[j];
      red[(1 * TY + ty) * N + tx * 4 + j] = pq[j];
    }
    __syncthreads();
    for (int col = tid; col < N; col += 256){
      float s = 0.f, q = 0.f;
      #pragma unroll
      for (int t2 = 0; t2 < TY; ++t2){
        s += red[(0 * TY + t2) * N + col];
        q += red[(1 * TY + t2) * N + col];
      }
      atomicAdd(&stats[col], s);
      atomicAdd(&stats[N + col], q);
    }
  }
}

__global__ void k_bn(const float* __restrict__ stats, const float* __restrict__ g,
                     const float* __restrict__ beta, float* __restrict__ scale,
                     float* __restrict__ shift, float inv_n){
  int c = threadIdx.x;   // 64 threads
  float mean = stats[c] * inv_n;
  float var  = stats[64 + c] * inv_n - mean * mean;
  float sc   = g[c] * rsqrtf(var + 1e-5f);
  scale[c] = sc;
  shift[c] = beta[c] - mean * sc;
}

inline int cdiv(int a, int b){ return (a + b - 1) / b; }

} // namespace

extern "C" void kernel_launch(void* const* d_in, const int* in_sizes, int n_in,
                              void* d_out, int out_size, void* d_ws, size_t ws_size,
                              hipStream_t stream){
  const float* features = (const float*)d_in[0];
  const float* v_fea    = (const float*)d_in[1];
  const int*   inv      = (const int*)d_in[2];
  const int*   cil      = (const int*)d_in[3];
  const int*   cin      = (const int*)d_in[4];
  const float* W_in  = (const float*)d_in[5];
  const float* b_in  = (const float*)d_in[6];
  const float* W1    = (const float*)d_in[7];
  const float* b1    = (const float*)d_in[8];
  const float* g1    = (const float*)d_in[9];
  const float* beta1 = (const float*)d_in[10];
  const float* W2    = (const float*)d_in[11];
  const float* b2    = (const float*)d_in[12];
  const float* g2    = (const float*)d_in[13];
  const float* beta2 = (const float*)d_in[14];
  const float* W3    = (const float*)d_in[15];
  const float* b3    = (const float*)d_in[16];
  const float* Wo1   = (const float*)d_in[17];
  const float* bo1   = (const float*)d_in[18];
  const float* Wo2   = (const float*)d_in[19];
  const float* bo2   = (const float*)d_in[20];

  // ---- workspace layout ----
  float* ws = (float*)d_ws;
  float* ds_mean = ws;                               // ND*C (t aliases later)
  float* h1      = ds_mean + (size_t)ND * C;         // ND*64
  float* h2      = h1 + (size_t)ND * 64;             // ND*64
  float* stats   = h2 + (size_t)ND * 64;             // 512
  float* big     = stats + 512;                      // NV*C: hm->identity->y->z
  int*   ip      = (int*)(big + (size_t)NV * C);
  int*   histp   = ip;                 // NV2
  int*   histd   = histp + NV2;        // ND       (contiguous with histp for memset)
  int*   offp    = histd + ND;         // NV2+1
  int*   nextp   = offp + NV2 + 1;     // NV2
  int*   offd    = nextp + NV2;        // ND+1
  int*   nextd   = offd + ND + 1;      // ND
  int*   pid     = nextd + ND;         // NPTS
  int*   vsrc    = pid + NPTS;         // NPTS
  int*   vid     = vsrc + NPTS;        // NV

  float* t      = ds_mean;        // alias: ds_mean dead after step 2, t born step 5
  float* stats1 = stats;
  float* stats2 = stats + 128;
  float* scale1 = stats + 256;
  float* shift1 = stats + 320;
  float* scale2 = stats + 384;
  float* shift2 = stats + 448;

  // zero: histp+histd (one region) and BN stat sums
  hipMemsetAsync(histp, 0, (size_t)(NV2 + ND) * sizeof(int), stream);
  hipMemsetAsync(stats, 0, 256 * sizeof(float), stream);

  // ---- build segment point-lists (counting sort) ----
  k_hist<<<cdiv(NPTS, 256), 256, 0, stream>>>(cin, NPTS, histp);
  k_hist<<<cdiv(NV, 256), 256, 0, stream>>>(inv, NV, histd);
  k_scan<<<1, 1024, 0, stream>>>(histp, offp, nextp, NV2);
  k_scan<<<1, 1024, 0, stream>>>(histd, offd, nextd, ND);
  k_order_p<<<cdiv(NPTS, 256), 256, 0, stream>>>(cin, cil, nextp, pid, vsrc);
  k_order_ds<<<cdiv(NV, 256), 256, 0, stream>>>(inv, nextd, vid);

  // 1) ds_mean = segment_mean(features+v_fea, inv)   [atomic-free]
  k_segmean_ds<<<cdiv(ND, 4), 256, 0, stream>>>(features, v_fea, offd, vid, ds_mean);

  // 2) h1 = lrelu(ds_mean @ W1 + b1), BN1 stats
  k_gemm<128, 64, true, true, false, false, false, true>
      <<<cdiv(ND, 64), 256, 0, stream>>>(ds_mean, nullptr, nullptr, nullptr,
                                          W1, b1, nullptr, nullptr, h1, stats1, ND);
  k_bn<<<1, 64, 0, stream>>>(stats1, g1, beta1, scale1, shift1, 1.f / ND);

  // 3) h2 = lrelu(bn1(h1) @ W2 + b2), BN2 stats
  k_gemm<64, 64, true, true, true, false, false, true>
      <<<cdiv(ND, 64), 256, 0, stream>>>(h1, nullptr, scale1, shift1,
                                          W2, b2, nullptr, nullptr, h2, stats2, ND);
  k_bn<<<1, 64, 0, stream>>>(stats2, g2, beta2, scale2, shift2, 1.f / ND);

  // 4) hm = lrelu(bn2(h2) @ W3 + b3) -> big
  k_gemm<64, 128, true, false, true, false, false, true>
      <<<cdiv(ND, 64), 256, 0, stream>>>(h2, nullptr, scale2, shift2,
                                          W3, b3, nullptr, nullptr, big, nullptr, ND);

  // 5) t = hm @ Wo1_bot + bo1   (t aliases ds_mean, dead now)
  k_gemm<128, 128, false, false, false, false, false, true>
      <<<cdiv(ND, 64), 256, 0, stream>>>(big, nullptr, nullptr, nullptr,
                                          Wo1 + (size_t)C * C, bo1, nullptr, nullptr,
                                          t, nullptr, ND);

  // 6) identity = lrelu((features+v_fea) @ W_in + b_in) -> big
  k_gemm<128, 128, true, false, false, true, false, true>
      <<<cdiv(NV, 64), 256, 0, stream>>>(features, v_fea, nullptr, nullptr,
                                          W_in, b_in, nullptr, nullptr, big, nullptr, NV);

  // 7) y = lrelu(identity @ Wo1_top + t[inv]) -> big in place
  k_gemm<128, 128, true, false, false, false, true, false>
      <<<cdiv(NV, 64), 256, 0, stream>>>(big, nullptr, nullptr, nullptr,
                                          Wo1, nullptr, t, inv, big, nullptr, NV);

  // 8) z = y @ Wo2 + bo2 -> big in place
  k_gemm<128, 128, false, false, false, false, false, true>
      <<<cdiv(NV, 64), 256, 0, stream>>>(big, nullptr, nullptr, nullptr,
                                          Wo2, bo2, nullptr, nullptr, big, nullptr, NV);

  // 9) fused: per-segment mean of z rows -> broadcast to out point rows
  k_segmean_p<<<cdiv(NV2, 4), 256, 0, stream>>>(big, offp, pid, vsrc, (float*)d_out);

  (void)in_sizes; (void)n_in; (void)out_size; (void)ws_size;
}

// Round 4
// 509.325 us; speedup vs baseline: 1.3472x; 1.3472x over previous
//
#include <hip/hip_runtime.h>

#define DEVI static __device__ __forceinline__

namespace {

constexpr int NV   = 120000;
constexpr int ND   = 30000;
constexpr int NV2  = 60000;
constexpr int NPTS = 400000;
constexpr int C    = 128;

constexpr int NSEG  = NV2 + ND;        // combined histogram length (90000)
constexpr int TOTAL = NPTS + NV;       // combined scan total
constexpr int ST    = 512;             // scan tile (elements per block)

DEVI float lrelu(float x){ return x > 0.f ? x : 0.1f*x; }

// ======== sort machinery: histogram -> hierarchical scan -> order-scatter ====

__global__ void k_hist(const int* __restrict__ seg, int n, int* __restrict__ hist){
  int i = blockIdx.x * blockDim.x + threadIdx.x;
  if (i < n) atomicAdd(&hist[seg[i]], 1);
}

// pass 1: per-tile sums (176 blocks x 256 thr, 2 elems/thr)
__global__ __launch_bounds__(256) void k_tilesum(const int* __restrict__ h, int n,
                                                 int* __restrict__ ts){
  __shared__ int red[256];
  int base = blockIdx.x * ST;
  int t = threadIdx.x;
  int a0 = base + t, a1 = base + t + 256;
  red[t] = (a0 < n ? h[a0] : 0) + (a1 < n ? h[a1] : 0);
  __syncthreads();
  for (int d = 128; d > 0; d >>= 1){
    if (t < d) red[t] += red[t + d];
    __syncthreads();
  }
  if (t == 0) ts[blockIdx.x] = red[0];
}

// pass 2: single-block exclusive scan of tile sums (nt <= 256)
__global__ __launch_bounds__(256) void k_scantiles(int* __restrict__ ts, int nt){
  __shared__ int ls[256];
  int t = threadIdx.x;
  ls[t] = t < nt ? ts[t] : 0;
  __syncthreads();
  for (int d = 1; d < 256; d <<= 1){
    int v = t >= d ? ls[t - d] : 0;
    __syncthreads();
    ls[t] += v;
    __syncthreads();
  }
  if (t < nt) ts[t] = (t == 0) ? 0 : ls[t - 1];
}

// pass 3: per-tile exclusive scan + global tile offset -> off[], next[]
__global__ __launch_bounds__(256) void k_scanwrite(
    const int* __restrict__ h, const int* __restrict__ ts, int n,
    int* __restrict__ off, int* __restrict__ next){
  __shared__ int ls[256];
  int base = blockIdx.x * ST;
  int t = threadIdx.x;
  int i0 = base + 2 * t, i1 = i0 + 1;
  int v0 = (i0 < n) ? h[i0] : 0;
  int v1 = (i1 < n) ? h[i1] : 0;
  ls[t] = v0 + v1;
  __syncthreads();
  for (int d = 1; d < 256; d <<= 1){
    int v = t >= d ? ls[t - d] : 0;
    __syncthreads();
    ls[t] += v;
    __syncthreads();
  }
  int ex = ts[blockIdx.x] + ((t == 0) ? 0 : ls[t - 1]);
  if (i0 < n){ off[i0] = ex;      next[i0] = ex; }
  if (i1 < n){ off[i1] = ex + v0; next[i1] = ex + v0; }
  if (blockIdx.x == 0 && t == 0) off[n] = TOTAL;
}

// points: record point id and its source voxel per segment slot
__global__ void k_order_p(const int* __restrict__ cin, const int* __restrict__ cil,
                          int* __restrict__ next, int* __restrict__ pid,
                          int* __restrict__ vsrc){
  int p = blockIdx.x * blockDim.x + threadIdx.x;
  if (p < NPTS){
    int s = cin[p];
    int idx = atomicAdd(&next[s], 1);
    pid[idx]  = p;
    vsrc[idx] = cil[p];
  }
}

// voxels: record voxel id per downsample-segment slot (combined-scan bias NPTS)
__global__ void k_order_ds(const int* __restrict__ inv, int* __restrict__ next,
                           int* __restrict__ vid){
  int v = blockIdx.x * blockDim.x + threadIdx.x;
  if (v < NV){
    int d = inv[v];
    int idx = atomicAdd(&next[NV2 + d], 1) - NPTS;
    vid[idx] = v;
  }
}

// ======== segmented means (atomic-free): one wave per segment ========

// ds_mean[d] = mean over {features[v]+v_fea[v] : inv[v]=d}; zero if empty
__global__ __launch_bounds__(256) void k_segmean_ds(
    const float* __restrict__ f, const float* __restrict__ vf,
    const int* __restrict__ off, const int* __restrict__ vid,
    float* __restrict__ ds_mean){
  int s = blockIdx.x * 4 + (threadIdx.x >> 6);
  if (s >= ND) return;
  int lane = threadIdx.x & 63;
  int start = off[NV2 + s] - NPTS, end = off[NV2 + s + 1] - NPTS;
  float2 acc = make_float2(0.f, 0.f);
  for (int j = start; j < end; ++j){
    int v = vid[j];
    float2 a = *(const float2*)(f  + (size_t)v * C + lane * 2);
    float2 b = *(const float2*)(vf + (size_t)v * C + lane * 2);
    acc.x += a.x + b.x; acc.y += a.y + b.y;
  }
  float invn = 1.f / (float)max(end - start, 1);
  acc.x *= invn; acc.y *= invn;
  *(float2*)(ds_mean + (size_t)s * C + lane * 2) = acc;
}

// per next-scale segment: mean of z[vsrc[j]] rows, written directly to ALL its
// output point rows (fuses divide + final gather; p_mean never materialized)
__global__ __launch_bounds__(256) void k_segmean_p(
    const float* __restrict__ z, const int* __restrict__ off,
    const int* __restrict__ pid, const int* __restrict__ vsrc,
    float* __restrict__ out){
  int s = blockIdx.x * 4 + (threadIdx.x >> 6);
  if (s >= NV2) return;
  int lane = threadIdx.x & 63;
  int start = off[s], end = off[s + 1];
  float2 acc = make_float2(0.f, 0.f);
  for (int j = start; j < end; ++j){
    int v = vsrc[j];
    float2 a = *(const float2*)(z + (size_t)v * C + lane * 2);
    acc.x += a.x; acc.y += a.y;
  }
  float invn = 1.f / (float)max(end - start, 1);
  acc.x *= invn; acc.y *= invn;
  for (int j = start; j < end; ++j){
    int p = pid[j];
    *(float2*)(out + (size_t)p * C + lane * 2) = acc;
  }
}

// ======== generic row-tiled f32 GEMM (unchanged core) ========
template<int K, int N, bool LRELU, bool STATS, bool PRESCALE,
         bool TWOIN, bool ROWADD, bool BIAS>
__global__ __launch_bounds__(256) void k_gemm(
    const float* __restrict__ A, const float* __restrict__ A2,
    const float* __restrict__ scale, const float* __restrict__ shift,
    const float* __restrict__ W, const float* __restrict__ bias,
    const float* __restrict__ rowtab, const int* __restrict__ rowidx,
    float* __restrict__ out, float* __restrict__ stats, int M)
{
  constexpr int BM = 64;
  constexpr int G  = N / 4;
  constexpr int TY = 256 / G;
  constexpr int R  = BM / TY;
  constexpr int KV = K / 4;

  __shared__ float At[K][BM + 4];
  __shared__ int   sidx[ROWADD ? BM : 1];
  __shared__ float red[STATS ? 2 * TY * N : 1];

  const int tid  = threadIdx.x;
  const int tx   = tid % G;
  const int ty   = tid / G;
  const int row0 = blockIdx.x * BM;

  for (int i = tid; i < BM * KV; i += 256){
    int r  = i / KV;
    int kc = (i % KV) * 4;
    int row = row0 + r;
    float4 v = make_float4(0.f, 0.f, 0.f, 0.f);
    if (row < M){
      v = *(const float4*)(A + (size_t)row * K + kc);
      if constexpr (TWOIN){
        float4 w = *(const float4*)(A2 + (size_t)row * K + kc);
        v.x += w.x; v.y += w.y; v.z += w.z; v.w += w.w;
      }
      if constexpr (PRESCALE){
        v.x = v.x * scale[kc + 0] + shift[kc + 0];
        v.y = v.y * scale[kc + 1] + shift[kc + 1];
        v.z = v.z * scale[kc + 2] + shift[kc + 2];
        v.w = v.w * scale[kc + 3] + shift[kc + 3];
      }
    }
    At[kc + 0][r] = v.x; At[kc + 1][r] = v.y;
    At[kc + 2][r] = v.z; At[kc + 3][r] = v.w;
  }
  if constexpr (ROWADD){
    for (int i = tid; i < BM; i += 256){
      int row = row0 + i;
      sidx[i] = row < M ? rowidx[row] : 0;
    }
  }
  __syncthreads();

  float acc[R][4];
  #pragma unroll
  for (int r = 0; r < R; ++r)
    for (int j = 0; j < 4; ++j) acc[r][j] = 0.f;

  #pragma unroll 4
  for (int k = 0; k < K; ++k){
    float4 w4 = *(const float4*)(W + (size_t)k * N + tx * 4);
    const float4* ap = (const float4*)&At[k][ty * R];
    #pragma unroll
    for (int rq = 0; rq < R / 4; ++rq){
      float4 a4 = ap[rq];
      float av[4] = {a4.x, a4.y, a4.z, a4.w};
      #pragma unroll
      for (int rr = 0; rr < 4; ++rr){
        int r = rq * 4 + rr;
        acc[r][0] += av[rr] * w4.x;
        acc[r][1] += av[rr] * w4.y;
        acc[r][2] += av[rr] * w4.z;
        acc[r][3] += av[rr] * w4.w;
      }
    }
  }

  float bx[4] = {0.f, 0.f, 0.f, 0.f};
  if constexpr (BIAS){
    float4 b = *(const float4*)(bias + tx * 4);
    bx[0] = b.x; bx[1] = b.y; bx[2] = b.z; bx[3] = b.w;
  }

  float ps[4] = {0.f,0.f,0.f,0.f}, pq[4] = {0.f,0.f,0.f,0.f};
  #pragma unroll
  for (int r = 0; r < R; ++r){
    int row = row0 + ty * R + r;
    if (row < M){
      float o[4];
      #pragma unroll
      for (int j = 0; j < 4; ++j) o[j] = acc[r][j] + bx[j];
      if constexpr (ROWADD){
        int d = sidx[ty * R + r];
        float4 tv = *(const float4*)(rowtab + (size_t)d * N + tx * 4);
        o[0] += tv.x; o[1] += tv.y; o[2] += tv.z; o[3] += tv.w;
      }
      if constexpr (LRELU){
        #pragma unroll
        for (int j = 0; j < 4; ++j) o[j] = lrelu(o[j]);
      }
      *(float4*)(out + (size_t)row * N + tx * 4) = make_float4(o[0], o[1], o[2], o[3]);
      if constexpr (STATS){
        #pragma unroll
        for (int j = 0; j < 4; ++j){ ps[j] += o[j]; pq[j] += o[j] * o[j]; }
      }
    }
  }

  if constexpr (STATS){
    #pragma unroll
    for (int j = 0; j < 4; ++j){
      red[(0 * TY + ty) * N + tx * 4 + j] = ps[j];
      red[(1 * TY + ty) * N + tx * 4 + j] = pq[j];
    }
    __syncthreads();
    for (int col = tid; col < N; col += 256){
      float s = 0.f, q = 0.f;
      #pragma unroll
      for (int t2 = 0; t2 < TY; ++t2){
        s += red[(0 * TY + t2) * N + col];
        q += red[(1 * TY + t2) * N + col];
      }
      atomicAdd(&stats[col], s);
      atomicAdd(&stats[N + col], q);
    }
  }
}

__global__ void k_bn(const float* __restrict__ stats, const float* __restrict__ g,
                     const float* __restrict__ beta, float* __restrict__ scale,
                     float* __restrict__ shift, float inv_n){
  int c = threadIdx.x;   // 64 threads
  float mean = stats[c] * inv_n;
  float var  = stats[64 + c] * inv_n - mean * mean;
  float sc   = g[c] * rsqrtf(var + 1e-5f);
  scale[c] = sc;
  shift[c] = beta[c] - mean * sc;
}

inline int cdiv(int a, int b){ return (a + b - 1) / b; }

} // namespace

extern "C" void kernel_launch(void* const* d_in, const int* in_sizes, int n_in,
                              void* d_out, int out_size, void* d_ws, size_t ws_size,
                              hipStream_t stream){
  const float* features = (const float*)d_in[0];
  const float* v_fea    = (const float*)d_in[1];
  const int*   inv      = (const int*)d_in[2];
  const int*   cil      = (const int*)d_in[3];
  const int*   cin      = (const int*)d_in[4];
  const float* W_in  = (const float*)d_in[5];
  const float* b_in  = (const float*)d_in[6];
  const float* W1    = (const float*)d_in[7];
  const float* b1    = (const float*)d_in[8];
  const float* g1    = (const float*)d_in[9];
  const float* beta1 = (const float*)d_in[10];
  const float* W2    = (const float*)d_in[11];
  const float* b2    = (const float*)d_in[12];
  const float* g2    = (const float*)d_in[13];
  const float* beta2 = (const float*)d_in[14];
  const float* W3    = (const float*)d_in[15];
  const float* b3    = (const float*)d_in[16];
  const float* Wo1   = (const float*)d_in[17];
  const float* bo1   = (const float*)d_in[18];
  const float* Wo2   = (const float*)d_in[19];
  const float* bo2   = (const float*)d_in[20];

  // ---- workspace layout ----
  float* ws = (float*)d_ws;
  float* ds_mean = ws;                               // ND*C (t aliases later)
  float* h1      = ds_mean + (size_t)ND * C;         // ND*64
  float* h2      = h1 + (size_t)ND * 64;             // ND*64
  float* stats   = h2 + (size_t)ND * 64;             // 512
  float* big     = stats + 512;                      // NV*C: hm->identity->y->z
  int*   ip      = (int*)(big + (size_t)NV * C);
  int*   histc   = ip;                  // NSEG  = [histp(NV2) | histd(ND)]
  int*   off     = histc + NSEG;        // NSEG+1 (combined exclusive scan)
  int*   next    = off + NSEG + 1;      // NSEG
  int*   tsum    = next + NSEG;         // scan tiles (<=256)
  int*   pid     = tsum + 256;          // NPTS
  int*   vsrc    = pid + NPTS;          // NPTS
  int*   vid     = vsrc + NPTS;         // NV

  float* t      = ds_mean;        // alias: ds_mean dead after step 2, t born step 5
  float* stats1 = stats;
  float* stats2 = stats + 128;
  float* scale1 = stats + 256;
  float* shift1 = stats + 320;
  float* scale2 = stats + 384;
  float* shift2 = stats + 448;

  const int NT = cdiv(NSEG, ST);   // 176 scan tiles

  // zero: combined histogram and BN stat sums
  hipMemsetAsync(histc, 0, (size_t)NSEG * sizeof(int), stream);
  hipMemsetAsync(stats, 0, 256 * sizeof(float), stream);

  // ---- build segment point-lists (counting sort, hierarchical scan) ----
  k_hist<<<cdiv(NPTS, 256), 256, 0, stream>>>(cin, NPTS, histc);
  k_hist<<<cdiv(NV, 256), 256, 0, stream>>>(inv, NV, histc + NV2);
  k_tilesum<<<NT, 256, 0, stream>>>(histc, NSEG, tsum);
  k_scantiles<<<1, 256, 0, stream>>>(tsum, NT);
  k_scanwrite<<<NT, 256, 0, stream>>>(histc, tsum, NSEG, off, next);
  k_order_p<<<cdiv(NPTS, 256), 256, 0, stream>>>(cin, cil, next, pid, vsrc);
  k_order_ds<<<cdiv(NV, 256), 256, 0, stream>>>(inv, next, vid);

  // 1) ds_mean = segment_mean(features+v_fea, inv)   [atomic-free]
  k_segmean_ds<<<cdiv(ND, 4), 256, 0, stream>>>(features, v_fea, off, vid, ds_mean);

  // 2) h1 = lrelu(ds_mean @ W1 + b1), BN1 stats
  k_gemm<128, 64, true, true, false, false, false, true>
      <<<cdiv(ND, 64), 256, 0, stream>>>(ds_mean, nullptr, nullptr, nullptr,
                                          W1, b1, nullptr, nullptr, h1, stats1, ND);
  k_bn<<<1, 64, 0, stream>>>(stats1, g1, beta1, scale1, shift1, 1.f / ND);

  // 3) h2 = lrelu(bn1(h1) @ W2 + b2), BN2 stats
  k_gemm<64, 64, true, true, true, false, false, true>
      <<<cdiv(ND, 64), 256, 0, stream>>>(h1, nullptr, scale1, shift1,
                                          W2, b2, nullptr, nullptr, h2, stats2, ND);
  k_bn<<<1, 64, 0, stream>>>(stats2, g2, beta2, scale2, shift2, 1.f / ND);

  // 4) hm = lrelu(bn2(h2) @ W3 + b3) -> big
  k_gemm<64, 128, true, false, true, false, false, true>
      <<<cdiv(ND, 64), 256, 0, stream>>>(h2, nullptr, scale2, shift2,
                                          W3, b3, nullptr, nullptr, big, nullptr, ND);

  // 5) t = hm @ Wo1_bot + bo1   (t aliases ds_mean, dead now)
  k_gemm<128, 128, false, false, false, false, false, true>
      <<<cdiv(ND, 64), 256, 0, stream>>>(big, nullptr, nullptr, nullptr,
                                          Wo1 + (size_t)C * C, bo1, nullptr, nullptr,
                                          t, nullptr, ND);

  // 6) identity = lrelu((features+v_fea) @ W_in + b_in) -> big
  k_gemm<128, 128, true, false, false, true, false, true>
      <<<cdiv(NV, 64), 256, 0, stream>>>(features, v_fea, nullptr, nullptr,
                                          W_in, b_in, nullptr, nullptr, big, nullptr, NV);

  // 7) y = lrelu(identity @ Wo1_top + t[inv]) -> big in place
  k_gemm<128, 128, true, false, false, false, true, false>
      <<<cdiv(NV, 64), 256, 0, stream>>>(big, nullptr, nullptr, nullptr,
                                          Wo1, nullptr, t, inv, big, nullptr, NV);

  // 8) z = y @ Wo2 + bo2 -> big in place
  k_gemm<128, 128, false, false, false, false, false, true>
      <<<cdiv(NV, 64), 256, 0, stream>>>(big, nullptr, nullptr, nullptr,
                                          Wo2, bo2, nullptr, nullptr, big, nullptr, NV);

  // 9) fused: per-segment mean of z rows -> broadcast to out point rows
  k_segmean_p<<<cdiv(NV2, 4), 256, 0, stream>>>(big, off, pid, vsrc, (float*)d_out);

  (void)in_sizes; (void)n_in; (void)out_size; (void)ws_size;
}

// Round 5
// 420.645 us; speedup vs baseline: 1.6312x; 1.2108x over previous
//
#include <hip/hip_runtime.h>

#define DEVI static __device__ __forceinline__

namespace {

constexpr int NV   = 120000;
constexpr int ND   = 30000;
constexpr int NV2  = 60000;
constexpr int NPTS = 400000;
constexpr int C    = 128;

constexpr int NSEG  = NV2 + ND;        // combined histogram length (90000)
constexpr int TOTAL = NPTS + NV;       // combined scan total
constexpr int ST    = 512;             // scan tile (elements per block)

typedef __attribute__((ext_vector_type(8))) short bf16x8;   // 8 bf16 = 4 VGPR
typedef __attribute__((ext_vector_type(4))) float f32x4;    // MFMA accumulator

DEVI float lrelu(float x){ return x > 0.f ? x : 0.1f*x; }

DEVI unsigned short f2bf(float f){            // f32 -> bf16 RNE
  unsigned u = __float_as_uint(f);
  return (unsigned short)((u + 0x7FFFu + ((u >> 16) & 1u)) >> 16);
}
DEVI float bf2f(unsigned short h){ return __uint_as_float((unsigned)h << 16); }

// ======== sort machinery: histogram -> hierarchical scan -> order-scatter ====

__global__ void k_hist(const int* __restrict__ seg, int n, int* __restrict__ hist){
  int i = blockIdx.x * blockDim.x + threadIdx.x;
  if (i < n) atomicAdd(&hist[seg[i]], 1);
}

__global__ __launch_bounds__(256) void k_tilesum(const int* __restrict__ h, int n,
                                                 int* __restrict__ ts){
  __shared__ int red[256];
  int base = blockIdx.x * ST;
  int t = threadIdx.x;
  int a0 = base + t, a1 = base + t + 256;
  red[t] = (a0 < n ? h[a0] : 0) + (a1 < n ? h[a1] : 0);
  __syncthreads();
  for (int d = 128; d > 0; d >>= 1){
    if (t < d) red[t] += red[t + d];
    __syncthreads();
  }
  if (t == 0) ts[blockIdx.x] = red[0];
}

__global__ __launch_bounds__(256) void k_scantiles(int* __restrict__ ts, int nt){
  __shared__ int ls[256];
  int t = threadIdx.x;
  ls[t] = t < nt ? ts[t] : 0;
  __syncthreads();
  for (int d = 1; d < 256; d <<= 1){
    int v = t >= d ? ls[t - d] : 0;
    __syncthreads();
    ls[t] += v;
    __syncthreads();
  }
  if (t < nt) ts[t] = (t == 0) ? 0 : ls[t - 1];
}

__global__ __launch_bounds__(256) void k_scanwrite(
    const int* __restrict__ h, const int* __restrict__ ts, int n,
    int* __restrict__ off, int* __restrict__ next){
  __shared__ int ls[256];
  int base = blockIdx.x * ST;
  int t = threadIdx.x;
  int i0 = base + 2 * t, i1 = i0 + 1;
  int v0 = (i0 < n) ? h[i0] : 0;
  int v1 = (i1 < n) ? h[i1] : 0;
  ls[t] = v0 + v1;
  __syncthreads();
  for (int d = 1; d < 256; d <<= 1){
    int v = t >= d ? ls[t - d] : 0;
    __syncthreads();
    ls[t] += v;
    __syncthreads();
  }
  int ex = ts[blockIdx.x] + ((t == 0) ? 0 : ls[t - 1]);
  if (i0 < n){ off[i0] = ex;      next[i0] = ex; }
  if (i1 < n){ off[i1] = ex + v0; next[i1] = ex + v0; }
  if (blockIdx.x == 0 && t == 0) off[n] = TOTAL;
}

__global__ void k_order_p(const int* __restrict__ cin, const int* __restrict__ cil,
                          int* __restrict__ next, int* __restrict__ pid,
                          int* __restrict__ vsrc){
  int p = blockIdx.x * blockDim.x + threadIdx.x;
  if (p < NPTS){
    int s = cin[p];
    int idx = atomicAdd(&next[s], 1);
    pid[idx]  = p;
    vsrc[idx] = cil[p];
  }
}

__global__ void k_order_ds(const int* __restrict__ inv, int* __restrict__ next,
                           int* __restrict__ vid){
  int v = blockIdx.x * blockDim.x + threadIdx.x;
  if (v < NV){
    int d = inv[v];
    int idx = atomicAdd(&next[NV2 + d], 1) - NPTS;
    vid[idx] = v;
  }
}

// ======== segmented means (atomic-free): one wave per segment ========

__global__ __launch_bounds__(256) void k_segmean_ds(
    const float* __restrict__ f, const float* __restrict__ vf,
    const int* __restrict__ off, const int* __restrict__ vid,
    float* __restrict__ ds_mean){
  int s = blockIdx.x * 4 + (threadIdx.x >> 6);
  if (s >= ND) return;
  int lane = threadIdx.x & 63;
  int start = off[NV2 + s] - NPTS, end = off[NV2 + s + 1] - NPTS;
  float2 acc = make_float2(0.f, 0.f);
  for (int j = start; j < end; ++j){
    int v = vid[j];
    float2 a = *(const float2*)(f  + (size_t)v * C + lane * 2);
    float2 b = *(const float2*)(vf + (size_t)v * C + lane * 2);
    acc.x += a.x + b.x; acc.y += a.y + b.y;
  }
  float invn = 1.f / (float)max(end - start, 1);
  acc.x *= invn; acc.y *= invn;
  *(float2*)(ds_mean + (size_t)s * C + lane * 2) = acc;
}

__global__ __launch_bounds__(256) void k_segmean_p(
    const float* __restrict__ z, const int* __restrict__ off,
    const int* __restrict__ pid, const int* __restrict__ vsrc,
    float* __restrict__ out){
  int s = blockIdx.x * 4 + (threadIdx.x >> 6);
  if (s >= NV2) return;
  int lane = threadIdx.x & 63;
  int start = off[s], end = off[s + 1];
  float2 acc = make_float2(0.f, 0.f);
  for (int j = start; j < end; ++j){
    int v = vsrc[j];
    float2 a = *(const float2*)(z + (size_t)v * C + lane * 2);
    acc.x += a.x; acc.y += a.y;
  }
  float invn = 1.f / (float)max(end - start, 1);
  acc.x *= invn; acc.y *= invn;
  for (int j = start; j < end; ++j){
    int p = pid[j];
    *(float2*)(out + (size_t)p * C + lane * 2) = acc;
  }
}

// ======== MFMA path for the 128x128 GEMMs (split-bf16, ~f32 accuracy) ========

// Pack W[128][128] f32 into mfma_f32_16x16x32_bf16 B-fragment order, hi+lo.
// frag id = (nt*4+ks)*64+lane; lane holds B[k][col]: col=lane&15,
// k = ks*32+(lane>>4)*8+j, j=0..7. 2048 frags -> grid 8 x 256.
__global__ __launch_bounds__(256) void k_pack(const float* __restrict__ W,
                                              unsigned short* __restrict__ ph,
                                              unsigned short* __restrict__ pl){
  int frag = blockIdx.x * 256 + threadIdx.x;
  int lane = frag & 63;
  int ks = (frag >> 6) & 3;
  int nt = frag >> 8;
  int n  = nt * 16 + (lane & 15);
  int k0 = ks * 32 + (lane >> 4) * 8;
  int ob = frag * 8;
  #pragma unroll
  for (int j = 0; j < 8; ++j){
    float w = W[(size_t)(k0 + j) * 128 + n];
    unsigned short hi = f2bf(w);
    float lo = w - bf2f(hi);
    ph[ob + j] = hi;
    pl[ob + j] = f2bf(lo);
  }
}

// out[M,128] = epi( A[M,128] @ W ),  W pre-packed hi/lo.
// D = a_hi*w_hi + a_lo*w_hi + a_hi*w_lo  (lo*lo dropped, rel err ~2^-17).
// 4 waves/block, each wave owns a 16-row strip. No LDS, no barriers.
// A-frag: lane l holds A[m0+(l&15)][ks*32+(l>>4)*8 .. +7]
// D: col = nt*16+(l&15), row = m0+(l>>4)*4+reg   [m89-verified]
template<bool LRELU, bool TWOIN, bool ROWADD, bool BIAS>
__global__ __launch_bounds__(256) void k_mgemm(
    const float* __restrict__ A, const float* __restrict__ A2,
    const unsigned short* __restrict__ wh, const unsigned short* __restrict__ wl,
    const float* __restrict__ bias, const float* __restrict__ rowtab,
    const int* __restrict__ rowidx, float* __restrict__ out, int M)
{
  const int l  = threadIdx.x & 63;
  const int wv = threadIdx.x >> 6;
  const int m0 = blockIdx.x * 64 + wv * 16;
  if (m0 >= M) return;                       // M % 16 == 0 for all call sites
  const int row = m0 + (l & 15);
  const int kb  = (l >> 4) * 8;

  // load + split A fragments (f32 -> bf16 hi/lo), 8 contiguous K elems per lane
  bf16x8 ah[4], al[4];
  const float* ar  = A + (size_t)row * 128;
  #pragma unroll
  for (int ks = 0; ks < 4; ++ks){
    float4 v0 = *(const float4*)(ar + ks * 32 + kb);
    float4 v1 = *(const float4*)(ar + ks * 32 + kb + 4);
    if constexpr (TWOIN){
      const float* ar2 = A2 + (size_t)row * 128;
      float4 u0 = *(const float4*)(ar2 + ks * 32 + kb);
      float4 u1 = *(const float4*)(ar2 + ks * 32 + kb + 4);
      v0.x += u0.x; v0.y += u0.y; v0.z += u0.z; v0.w += u0.w;
      v1.x += u1.x; v1.y += u1.y; v1.z += u1.z; v1.w += u1.w;
    }
    float v[8] = {v0.x, v0.y, v0.z, v0.w, v1.x, v1.y, v1.z, v1.w};
    bf16x8 h, lo;
    #pragma unroll
    for (int j = 0; j < 8; ++j){
      unsigned short hb = f2bf(v[j]);
      h[j]  = (short)hb;
      lo[j] = (short)f2bf(v[j] - bf2f(hb));
    }
    ah[ks] = h; al[ks] = lo;
  }

  const int colb  = l & 15;
  const int rbase = m0 + (l >> 4) * 4;
  int rid[4];
  if constexpr (ROWADD){
    #pragma unroll
    for (int r = 0; r < 4; ++r) rid[r] = rowidx[rbase + r];
  }

  #pragma unroll
  for (int nt = 0; nt < 8; ++nt){
    f32x4 acc = {0.f, 0.f, 0.f, 0.f};
    #pragma unroll
    for (int ks = 0; ks < 4; ++ks){
      const size_t fo = (size_t)((nt * 4 + ks) * 64 + l) * 8;
      bf16x8 bh = *(const bf16x8*)(wh + fo);
      bf16x8 bl = *(const bf16x8*)(wl + fo);
      acc = __builtin_amdgcn_mfma_f32_16x16x32_bf16(ah[ks], bh, acc, 0, 0, 0);
      acc = __builtin_amdgcn_mfma_f32_16x16x32_bf16(al[ks], bh, acc, 0, 0, 0);
      acc = __builtin_amdgcn_mfma_f32_16x16x32_bf16(ah[ks], bl, acc, 0, 0, 0);
    }
    const int col = nt * 16 + colb;
    float bc = 0.f;
    if constexpr (BIAS) bc = bias[col];
    #pragma unroll
    for (int r = 0; r < 4; ++r){
      float o = acc[r] + bc;
      if constexpr (ROWADD) o += rowtab[(size_t)rid[r] * 128 + col];
      if constexpr (LRELU) o = lrelu(o);
      out[(size_t)(rbase + r) * 128 + col] = o;
    }
  }
}

// ======== f32 row-tiled GEMM (kept for the small ND-row BN stages) ========
template<int K, int N, bool LRELU, bool STATS, bool PRESCALE,
         bool TWOIN, bool ROWADD, bool BIAS>
__global__ __launch_bounds__(256) void k_gemm(
    const float* __restrict__ A, const float* __restrict__ A2,
    const float* __restrict__ scale, const float* __restrict__ shift,
    const float* __restrict__ W, const float* __restrict__ bias,
    const float* __restrict__ rowtab, const int* __restrict__ rowidx,
    float* __restrict__ out, float* __restrict__ stats, int M)
{
  constexpr int BM = 64;
  constexpr int G  = N / 4;
  constexpr int TY = 256 / G;
  constexpr int R  = BM / TY;
  constexpr int KV = K / 4;

  __shared__ float At[K][BM + 4];
  __shared__ int   sidx[ROWADD ? BM : 1];
  __shared__ float red[STATS ? 2 * TY * N : 1];

  const int tid  = threadIdx.x;
  const int tx   = tid % G;
  const int ty   = tid / G;
  const int row0 = blockIdx.x * BM;

  for (int i = tid; i < BM * KV; i += 256){
    int r  = i / KV;
    int kc = (i % KV) * 4;
    int row = row0 + r;
    float4 v = make_float4(0.f, 0.f, 0.f, 0.f);
    if (row < M){
      v = *(const float4*)(A + (size_t)row * K + kc);
      if constexpr (TWOIN){
        float4 w = *(const float4*)(A2 + (size_t)row * K + kc);
        v.x += w.x; v.y += w.y; v.z += w.z; v.w += w.w;
      }
      if constexpr (PRESCALE){
        v.x = v.x * scale[kc + 0] + shift[kc + 0];
        v.y = v.y * scale[kc + 1] + shift[kc + 1];
        v.z = v.z * scale[kc + 2] + shift[kc + 2];
        v.w = v.w * scale[kc + 3] + shift[kc + 3];
      }
    }
    At[kc + 0][r] = v.x; At[kc + 1][r] = v.y;
    At[kc + 2][r] = v.z; At[kc + 3][r] = v.w;
  }
  if constexpr (ROWADD){
    for (int i = tid; i < BM; i += 256){
      int row = row0 + i;
      sidx[i] = row < M ? rowidx[row] : 0;
    }
  }
  __syncthreads();

  float acc[R][4];
  #pragma unroll
  for (int r = 0; r < R; ++r)
    for (int j = 0; j < 4; ++j) acc[r][j] = 0.f;

  #pragma unroll 4
  for (int k = 0; k < K; ++k){
    float4 w4 = *(const float4*)(W + (size_t)k * N + tx * 4);
    const float4* ap = (const float4*)&At[k][ty * R];
    #pragma unroll
    for (int rq = 0; rq < R / 4; ++rq){
      float4 a4 = ap[rq];
      float av[4] = {a4.x, a4.y, a4.z, a4.w};
      #pragma unroll
      for (int rr = 0; rr < 4; ++rr){
        int r = rq * 4 + rr;
        acc[r][0] += av[rr] * w4.x;
        acc[r][1] += av[rr] * w4.y;
        acc[r][2] += av[rr] * w4.z;
        acc[r][3] += av[rr] * w4.w;
      }
    }
  }

  float bx[4] = {0.f, 0.f, 0.f, 0.f};
  if constexpr (BIAS){
    float4 b = *(const float4*)(bias + tx * 4);
    bx[0] = b.x; bx[1] = b.y; bx[2] = b.z; bx[3] = b.w;
  }

  float ps[4] = {0.f,0.f,0.f,0.f}, pq[4] = {0.f,0.f,0.f,0.f};
  #pragma unroll
  for (int r = 0; r < R; ++r){
    int row = row0 + ty * R + r;
    if (row < M){
      float o[4];
      #pragma unroll
      for (int j = 0; j < 4; ++j) o[j] = acc[r][j] + bx[j];
      if constexpr (ROWADD){
        int d = sidx[ty * R + r];
        float4 tv = *(const float4*)(rowtab + (size_t)d * N + tx * 4);
        o[0] += tv.x; o[1] += tv.y; o[2] += tv.z; o[3] += tv.w;
      }
      if constexpr (LRELU){
        #pragma unroll
        for (int j = 0; j < 4; ++j) o[j] = lrelu(o[j]);
      }
      *(float4*)(out + (size_t)row * N + tx * 4) = make_float4(o[0], o[1], o[2], o[3]);
      if constexpr (STATS){
        #pragma unroll
        for (int j = 0; j < 4; ++j){ ps[j] += o[j]; pq[j] += o[j] * o[j]; }
      }
    }
  }

  if constexpr (STATS){
    #pragma unroll
    for (int j = 0; j < 4; ++j){
      red[(0 * TY + ty) * N + tx * 4 + j] = ps[j];
      red[(1 * TY + ty) * N + tx * 4 + j] = pq[j];
    }
    __syncthreads();
    for (int col = tid; col < N; col += 256){
      float s = 0.f, q = 0.f;
      #pragma unroll
      for (int t2 = 0; t2 < TY; ++t2){
        s += red[(0 * TY + t2) * N + col];
        q += red[(1 * TY + t2) * N + col];
      }
      atomicAdd(&stats[col], s);
      atomicAdd(&stats[N + col], q);
    }
  }
}

__global__ void k_bn(const float* __restrict__ stats, const float* __restrict__ g,
                     const float* __restrict__ beta, float* __restrict__ scale,
                     float* __restrict__ shift, float inv_n){
  int c = threadIdx.x;   // 64 threads
  float mean = stats[c] * inv_n;
  float var  = stats[64 + c] * inv_n - mean * mean;
  float sc   = g[c] * rsqrtf(var + 1e-5f);
  scale[c] = sc;
  shift[c] = beta[c] - mean * sc;
}

inline int cdiv(int a, int b){ return (a + b - 1) / b; }

} // namespace

extern "C" void kernel_launch(void* const* d_in, const int* in_sizes, int n_in,
                              void* d_out, int out_size, void* d_ws, size_t ws_size,
                              hipStream_t stream){
  const float* features = (const float*)d_in[0];
  const float* v_fea    = (const float*)d_in[1];
  const int*   inv      = (const int*)d_in[2];
  const int*   cil      = (const int*)d_in[3];
  const int*   cin      = (const int*)d_in[4];
  const float* W_in  = (const float*)d_in[5];
  const float* b_in  = (const float*)d_in[6];
  const float* W1    = (const float*)d_in[7];
  const float* b1    = (const float*)d_in[8];
  const float* g1    = (const float*)d_in[9];
  const float* beta1 = (const float*)d_in[10];
  const float* W2    = (const float*)d_in[11];
  const float* b2    = (const float*)d_in[12];
  const float* g2    = (const float*)d_in[13];
  const float* beta2 = (const float*)d_in[14];
  const float* W3    = (const float*)d_in[15];
  const float* b3    = (const float*)d_in[16];
  const float* Wo1   = (const float*)d_in[17];
  const float* bo1   = (const float*)d_in[18];
  const float* Wo2   = (const float*)d_in[19];
  const float* bo2   = (const float*)d_in[20];

  // ---- workspace layout ----
  float* ws = (float*)d_ws;
  float* ds_mean = ws;                               // ND*C (t aliases later)
  float* h1      = ds_mean + (size_t)ND * C;         // ND*64
  float* h2      = h1 + (size_t)ND * 64;             // ND*64
  float* stats   = h2 + (size_t)ND * 64;             // 512
  float* big     = stats + 512;                      // NV*C: hm->identity->y->z
  int*   ip      = (int*)(big + (size_t)NV * C);
  int*   histc   = ip;                  // NSEG  = [histp(NV2) | histd(ND)]
  int*   off     = histc + NSEG;        // NSEG+1
  int*   next    = off + NSEG + 1;      // NSEG
  int*   tsum    = next + NSEG;         // scan tiles (<=256)
  int*   pid     = tsum + 256;          // NPTS
  int*   vsrc    = pid + NPTS;          // NPTS
  int*   vid     = vsrc + NPTS;         // NV
  // packed weights (16B-aligned), 8 x 16384 ushort = 256 KB
  unsigned short* pw =
      (unsigned short*)((((uintptr_t)(vid + NV)) + 15) & ~(uintptr_t)15);
  unsigned short* Win_h  = pw;
  unsigned short* Win_l  = pw + 1 * 16384;
  unsigned short* Wo1t_h = pw + 2 * 16384;
  unsigned short* Wo1t_l = pw + 3 * 16384;
  unsigned short* Wo1b_h = pw + 4 * 16384;
  unsigned short* Wo1b_l = pw + 5 * 16384;
  unsigned short* Wo2_h  = pw + 6 * 16384;
  unsigned short* Wo2_l  = pw + 7 * 16384;

  float* t      = ds_mean;        // alias: ds_mean dead after step 2, t born step 5
  float* stats1 = stats;
  float* stats2 = stats + 128;
  float* scale1 = stats + 256;
  float* shift1 = stats + 320;
  float* scale2 = stats + 384;
  float* shift2 = stats + 448;

  const int NT = cdiv(NSEG, ST);   // 176 scan tiles

  hipMemsetAsync(histc, 0, (size_t)NSEG * sizeof(int), stream);
  hipMemsetAsync(stats, 0, 256 * sizeof(float), stream);

  // ---- pack the four 128x128 weights into MFMA B-fragment order (hi/lo) ----
  k_pack<<<8, 256, 0, stream>>>(W_in,                 Win_h,  Win_l);
  k_pack<<<8, 256, 0, stream>>>(Wo1,                  Wo1t_h, Wo1t_l);
  k_pack<<<8, 256, 0, stream>>>(Wo1 + (size_t)C * C,  Wo1b_h, Wo1b_l);
  k_pack<<<8, 256, 0, stream>>>(Wo2,                  Wo2_h,  Wo2_l);

  // ---- build segment point-lists (counting sort, hierarchical scan) ----
  k_hist<<<cdiv(NPTS, 256), 256, 0, stream>>>(cin, NPTS, histc);
  k_hist<<<cdiv(NV, 256), 256, 0, stream>>>(inv, NV, histc + NV2);
  k_tilesum<<<NT, 256, 0, stream>>>(histc, NSEG, tsum);
  k_scantiles<<<1, 256, 0, stream>>>(tsum, NT);
  k_scanwrite<<<NT, 256, 0, stream>>>(histc, tsum, NSEG, off, next);
  k_order_p<<<cdiv(NPTS, 256), 256, 0, stream>>>(cin, cil, next, pid, vsrc);
  k_order_ds<<<cdiv(NV, 256), 256, 0, stream>>>(inv, next, vid);

  // 1) ds_mean = segment_mean(features+v_fea, inv)
  k_segmean_ds<<<cdiv(ND, 4), 256, 0, stream>>>(features, v_fea, off, vid, ds_mean);

  // 2) h1 = lrelu(ds_mean @ W1 + b1), BN1 stats   (f32 path)
  k_gemm<128, 64, true, true, false, false, false, true>
      <<<cdiv(ND, 64), 256, 0, stream>>>(ds_mean, nullptr, nullptr, nullptr,
                                          W1, b1, nullptr, nullptr, h1, stats1, ND);
  k_bn<<<1, 64, 0, stream>>>(stats1, g1, beta1, scale1, shift1, 1.f / ND);

  // 3) h2 = lrelu(bn1(h1) @ W2 + b2), BN2 stats   (f32 path)
  k_gemm<64, 64, true, true, true, false, false, true>
      <<<cdiv(ND, 64), 256, 0, stream>>>(h1, nullptr, scale1, shift1,
                                          W2, b2, nullptr, nullptr, h2, stats2, ND);
  k_bn<<<1, 64, 0, stream>>>(stats2, g2, beta2, scale2, shift2, 1.f / ND);

  // 4) hm = lrelu(bn2(h2) @ W3 + b3) -> big       (f32 path)
  k_gemm<64, 128, true, false, true, false, false, true>
      <<<cdiv(ND, 64), 256, 0, stream>>>(h2, nullptr, scale2, shift2,
                                          W3, b3, nullptr, nullptr, big, nullptr, ND);

  // 5) t = hm @ Wo1_bot + bo1                     (MFMA; t aliases ds_mean)
  k_mgemm<false, false, false, true><<<cdiv(ND, 64), 256, 0, stream>>>(
      big, nullptr, Wo1b_h, Wo1b_l, bo1, nullptr, nullptr, t, ND);

  // 6) identity = lrelu((features+v_fea) @ W_in + b_in) -> big   (MFMA)
  k_mgemm<true, true, false, true><<<cdiv(NV, 64), 256, 0, stream>>>(
      features, v_fea, Win_h, Win_l, b_in, nullptr, nullptr, big, NV);

  // 7) y = lrelu(identity @ Wo1_top + t[inv]) -> big in place    (MFMA)
  k_mgemm<true, false, true, false><<<cdiv(NV, 64), 256, 0, stream>>>(
      big, nullptr, Wo1t_h, Wo1t_l, nullptr, t, inv, big, NV);

  // 8) z = y @ Wo2 + bo2 -> big in place                         (MFMA)
  k_mgemm<false, false, false, true><<<cdiv(NV, 64), 256, 0, stream>>>(
      big, nullptr, Wo2_h, Wo2_l, bo2, nullptr, nullptr, big, NV);

  // 9) fused: per-segment mean of z rows -> broadcast to out point rows
  k_segmean_p<<<cdiv(NV2, 4), 256, 0, stream>>>(big, off, pid, vsrc, (float*)d_out);

  (void)in_sizes; (void)n_in; (void)out_size; (void)ws_size;
}

// Round 6
// 378.269 us; speedup vs baseline: 1.8140x; 1.1120x over previous
//
#include <hip/hip_runtime.h>

#define DEVI static __device__ __forceinline__

namespace {

constexpr int NV   = 120000;
constexpr int ND   = 30000;
constexpr int NV2  = 60000;
constexpr int NPTS = 400000;
constexpr int C    = 128;

constexpr int NSEG  = NV2 + ND;        // combined histogram length (90000)
constexpr int TOTAL = NPTS + NV;       // combined scan total
constexpr int ST    = 512;             // scan tile (elements per block)

typedef __attribute__((ext_vector_type(8))) short bf16x8;   // 8 bf16 = 4 VGPR
typedef __attribute__((ext_vector_type(4))) float f32x4;    // MFMA accumulator

DEVI float lrelu(float x){ return x > 0.f ? x : 0.1f*x; }

DEVI unsigned short f2bf(float f){            // f32 -> bf16 RNE
  unsigned u = __float_as_uint(f);
  return (unsigned short)((u + 0x7FFFu + ((u >> 16) & 1u)) >> 16);
}
DEVI float bf2f(unsigned short h){ return __uint_as_float((unsigned)h << 16); }

DEVI void split8(const float* v, bf16x8& h, bf16x8& lo){
  #pragma unroll
  for (int j = 0; j < 8; ++j){
    unsigned short hb = f2bf(v[j]);
    h[j]  = (short)hb;
    lo[j] = (short)f2bf(v[j] - bf2f(hb));
  }
}

// ======== sort machinery: histogram -> hierarchical scan -> order-scatter ====

// combined histogram: points into histc[0..NV2), voxels into histc[NV2..NSEG)
__global__ void k_hist2(const int* __restrict__ cin, const int* __restrict__ inv,
                        int* __restrict__ histc){
  int i = blockIdx.x * blockDim.x + threadIdx.x;
  if (i < NPTS) atomicAdd(&histc[cin[i]], 1);
  else if (i < TOTAL) atomicAdd(&histc[NV2 + inv[i - NPTS]], 1);
}

__global__ __launch_bounds__(256) void k_tilesum(const int* __restrict__ h, int n,
                                                 int* __restrict__ ts){
  __shared__ int red[256];
  int base = blockIdx.x * ST;
  int t = threadIdx.x;
  int a0 = base + t, a1 = base + t + 256;
  red[t] = (a0 < n ? h[a0] : 0) + (a1 < n ? h[a1] : 0);
  __syncthreads();
  for (int d = 128; d > 0; d >>= 1){
    if (t < d) red[t] += red[t + d];
    __syncthreads();
  }
  if (t == 0) ts[blockIdx.x] = red[0];
}

__global__ __launch_bounds__(256) void k_scantiles(int* __restrict__ ts, int nt){
  __shared__ int ls[256];
  int t = threadIdx.x;
  ls[t] = t < nt ? ts[t] : 0;
  __syncthreads();
  for (int d = 1; d < 256; d <<= 1){
    int v = t >= d ? ls[t - d] : 0;
    __syncthreads();
    ls[t] += v;
    __syncthreads();
  }
  if (t < nt) ts[t] = (t == 0) ? 0 : ls[t - 1];
}

__global__ __launch_bounds__(256) void k_scanwrite(
    const int* __restrict__ h, const int* __restrict__ ts, int n,
    int* __restrict__ off, int* __restrict__ next){
  __shared__ int ls[256];
  int base = blockIdx.x * ST;
  int t = threadIdx.x;
  int i0 = base + 2 * t, i1 = i0 + 1;
  int v0 = (i0 < n) ? h[i0] : 0;
  int v1 = (i1 < n) ? h[i1] : 0;
  ls[t] = v0 + v1;
  __syncthreads();
  for (int d = 1; d < 256; d <<= 1){
    int v = t >= d ? ls[t - d] : 0;
    __syncthreads();
    ls[t] += v;
    __syncthreads();
  }
  int ex = ts[blockIdx.x] + ((t == 0) ? 0 : ls[t - 1]);
  if (i0 < n){ off[i0] = ex;      next[i0] = ex; }
  if (i1 < n){ off[i1] = ex + v0; next[i1] = ex + v0; }
  if (blockIdx.x == 0 && t == 0) off[n] = TOTAL;
}

// combined order-scatter (point slots then voxel slots)
__global__ void k_order2(const int* __restrict__ cin, const int* __restrict__ cil,
                         const int* __restrict__ inv, int* __restrict__ next,
                         int* __restrict__ pid, int* __restrict__ vsrc,
                         int* __restrict__ vid){
  int i = blockIdx.x * blockDim.x + threadIdx.x;
  if (i < NPTS){
    int s = cin[i];
    int idx = atomicAdd(&next[s], 1);
    pid[idx]  = i;
    vsrc[idx] = cil[i];
  } else if (i < TOTAL){
    int v = i - NPTS;
    int idx = atomicAdd(&next[NV2 + inv[v]], 1) - NPTS;
    vid[idx] = v;
  }
}

// ======== segmented means (atomic-free): one wave per segment ========

__global__ __launch_bounds__(256) void k_segmean_ds(
    const float* __restrict__ f, const float* __restrict__ vf,
    const int* __restrict__ off, const int* __restrict__ vid,
    float* __restrict__ ds_mean){
  int s = blockIdx.x * 4 + (threadIdx.x >> 6);
  if (s >= ND) return;
  int lane = threadIdx.x & 63;
  int start = off[NV2 + s] - NPTS, end = off[NV2 + s + 1] - NPTS;
  float2 acc = make_float2(0.f, 0.f);
  for (int j = start; j < end; ++j){
    int v = vid[j];
    float2 a = *(const float2*)(f  + (size_t)v * C + lane * 2);
    float2 b = *(const float2*)(vf + (size_t)v * C + lane * 2);
    acc.x += a.x + b.x; acc.y += a.y + b.y;
  }
  float invn = 1.f / (float)max(end - start, 1);
  acc.x *= invn; acc.y *= invn;
  *(float2*)(ds_mean + (size_t)s * C + lane * 2) = acc;
}

__global__ __launch_bounds__(256) void k_segmean_p(
    const float* __restrict__ z, const int* __restrict__ off,
    const int* __restrict__ pid, const int* __restrict__ vsrc,
    float* __restrict__ out){
  int s = blockIdx.x * 4 + (threadIdx.x >> 6);
  if (s >= NV2) return;
  int lane = threadIdx.x & 63;
  int start = off[s], end = off[s + 1];
  float2 acc = make_float2(0.f, 0.f);
  for (int j = start; j < end; ++j){
    int v = vsrc[j];
    float2 a = *(const float2*)(z + (size_t)v * C + lane * 2);
    acc.x += a.x; acc.y += a.y;
  }
  float invn = 1.f / (float)max(end - start, 1);
  acc.x *= invn; acc.y *= invn;
  for (int j = start; j < end; ++j){
    int p = pid[j];
    *(float2*)(out + (size_t)p * C + lane * 2) = acc;
  }
}

// ======== MFMA path (split-bf16, ~f32 accuracy) ========

// Pack 4 weights W[128][128] into mfma_f32_16x16x32_bf16 B-fragment order.
// pw layout: [w][hi 16384 | lo 16384]. grid 32 x 256.
__global__ __launch_bounds__(256) void k_pack4(
    const float* __restrict__ W0, const float* __restrict__ W1,
    const float* __restrict__ W2, const float* __restrict__ W3,
    unsigned short* __restrict__ pw){
  int w = blockIdx.x >> 3;
  const float* W = (w == 0) ? W0 : (w == 1) ? W1 : (w == 2) ? W2 : W3;
  unsigned short* ph = pw + (size_t)w * 32768;
  unsigned short* pl = ph + 16384;
  int frag = (blockIdx.x & 7) * 256 + threadIdx.x;
  int lane = frag & 63;
  int ks = (frag >> 6) & 3;
  int nt = frag >> 8;
  int n  = nt * 16 + (lane & 15);
  int k0 = ks * 32 + (lane >> 4) * 8;
  int ob = frag * 8;
  #pragma unroll
  for (int j = 0; j < 8; ++j){
    float w_ = W[(size_t)(k0 + j) * 128 + n];
    unsigned short hi = f2bf(w_);
    ph[ob + j] = hi;
    pl[ob + j] = f2bf(w_ - bf2f(hi));
  }
}

// single-stage MFMA GEMM (kept for step 5: t = hm @ Wo1_bot + bo1)
// A-frag: lane l holds A[m0+(l&15)][ks*32+(l>>4)*8 .. +7]
// D: col = nt*16+(l&15), row = m0+(l>>4)*4+reg   [m89-verified]
template<bool LRELU, bool TWOIN, bool ROWADD, bool BIAS>
__global__ __launch_bounds__(256) void k_mgemm(
    const float* __restrict__ A, const float* __restrict__ A2,
    const unsigned short* __restrict__ wh, const unsigned short* __restrict__ wl,
    const float* __restrict__ bias, const float* __restrict__ rowtab,
    const int* __restrict__ rowidx, float* __restrict__ out, int M)
{
  const int l  = threadIdx.x & 63;
  const int wv = threadIdx.x >> 6;
  const int m0 = blockIdx.x * 64 + wv * 16;
  if (m0 >= M) return;
  const int row = m0 + (l & 15);
  const int kb  = (l >> 4) * 8;

  bf16x8 ah[4], al[4];
  const float* ar = A + (size_t)row * 128;
  #pragma unroll
  for (int ks = 0; ks < 4; ++ks){
    float v[8];
    *(float4*)&v[0] = *(const float4*)(ar + ks * 32 + kb);
    *(float4*)&v[4] = *(const float4*)(ar + ks * 32 + kb + 4);
    if constexpr (TWOIN){
      const float* ar2 = A2 + (size_t)row * 128;
      float u[8];
      *(float4*)&u[0] = *(const float4*)(ar2 + ks * 32 + kb);
      *(float4*)&u[4] = *(const float4*)(ar2 + ks * 32 + kb + 4);
      #pragma unroll
      for (int j = 0; j < 8; ++j) v[j] += u[j];
    }
    split8(v, ah[ks], al[ks]);
  }

  const int colb  = l & 15;
  const int rbase = m0 + (l >> 4) * 4;
  int rid[4];
  if constexpr (ROWADD){
    #pragma unroll
    for (int r = 0; r < 4; ++r) rid[r] = rowidx[rbase + r];
  }

  #pragma unroll
  for (int nt = 0; nt < 8; ++nt){
    f32x4 acc = {0.f, 0.f, 0.f, 0.f};
    #pragma unroll
    for (int ks = 0; ks < 4; ++ks){
      const size_t fo = (size_t)((nt * 4 + ks) * 64 + l) * 8;
      bf16x8 bh = *(const bf16x8*)(wh + fo);
      bf16x8 bl = *(const bf16x8*)(wl + fo);
      acc = __builtin_amdgcn_mfma_f32_16x16x32_bf16(ah[ks], bh, acc, 0, 0, 0);
      acc = __builtin_amdgcn_mfma_f32_16x16x32_bf16(al[ks], bh, acc, 0, 0, 0);
      acc = __builtin_amdgcn_mfma_f32_16x16x32_bf16(ah[ks], bl, acc, 0, 0, 0);
    }
    const int col = nt * 16 + colb;
    float bc = 0.f;
    if constexpr (BIAS) bc = bias[col];
    #pragma unroll
    for (int r = 0; r < 4; ++r){
      float o = acc[r] + bc;
      if constexpr (ROWADD) o += rowtab[(size_t)rid[r] * 128 + col];
      if constexpr (LRELU) o = lrelu(o);
      out[(size_t)(rbase + r) * 128 + col] = o;
    }
  }
}

// ======== fused identity -> y -> z chain (steps 6-8) ========
// Per wave: one 16-row strip held on-chip across all 3 stages.
// Stage epilogue -> per-wave LDS tile [16][132] f32 (132-stride: 16B-aligned,
// <=2-way banks) -> re-read in A-frag order -> split hi/lo -> next MFMA stage.
// No barriers: waves use disjoint LDS; per-wave DS ops are ordered.
constexpr int TS = 132;   // LDS tile row stride (floats)

__global__ __launch_bounds__(256) void k_fused3(
    const float* __restrict__ f, const float* __restrict__ vf,
    const unsigned short* __restrict__ wh1, const unsigned short* __restrict__ wl1,
    const unsigned short* __restrict__ wh2, const unsigned short* __restrict__ wl2,
    const unsigned short* __restrict__ wh3, const unsigned short* __restrict__ wl3,
    const float* __restrict__ b_in, const float* __restrict__ trow,
    const int* __restrict__ inv, const float* __restrict__ bo2,
    float* __restrict__ z, int M)
{
  __shared__ float tile[4][16 * TS];
  const int l  = threadIdx.x & 63;
  const int wv = threadIdx.x >> 6;
  const int m0 = blockIdx.x * 64 + wv * 16;
  if (m0 >= M) return;
  float* T = &tile[wv][0];
  const int colb  = l & 15;          // D col-within-16 / A-frag row
  const int g     = l >> 4;          // D row group / A-frag k-block
  const int rbase = m0 + g * 4;

  bf16x8 ah[4], al[4];
  f32x4  acc[8];

  // ---- stage A frags from global: x = f + vf, row m0+(l&15)
  {
    const float* ar  = f  + (size_t)(m0 + colb) * 128;
    const float* ar2 = vf + (size_t)(m0 + colb) * 128;
    #pragma unroll
    for (int ks = 0; ks < 4; ++ks){
      float v[8], u[8];
      *(float4*)&v[0] = *(const float4*)(ar  + ks * 32 + g * 8);
      *(float4*)&v[4] = *(const float4*)(ar  + ks * 32 + g * 8 + 4);
      *(float4*)&u[0] = *(const float4*)(ar2 + ks * 32 + g * 8);
      *(float4*)&u[4] = *(const float4*)(ar2 + ks * 32 + g * 8 + 4);
      #pragma unroll
      for (int j = 0; j < 8; ++j) v[j] += u[j];
      split8(v, ah[ks], al[ks]);
    }
  }

  #define RUN_STAGE(WH, WL)                                                  \
    _Pragma("unroll")                                                        \
    for (int nt = 0; nt < 8; ++nt){                                          \
      f32x4 a = {0.f, 0.f, 0.f, 0.f};                                        \
      _Pragma("unroll")                                                      \
      for (int ks = 0; ks < 4; ++ks){                                        \
        const size_t fo = (size_t)((nt * 4 + ks) * 64 + l) * 8;              \
        bf16x8 bh = *(const bf16x8*)((WH) + fo);                             \
        bf16x8 bl = *(const bf16x8*)((WL) + fo);                             \
        a = __builtin_amdgcn_mfma_f32_16x16x32_bf16(ah[ks], bh, a, 0, 0, 0); \
        a = __builtin_amdgcn_mfma_f32_16x16x32_bf16(al[ks], bh, a, 0, 0, 0); \
        a = __builtin_amdgcn_mfma_f32_16x16x32_bf16(ah[ks], bl, a, 0, 0, 0); \
      }                                                                      \
      acc[nt] = a;                                                           \
    }

  #define LOAD_FRAGS_FROM_LDS()                                              \
    _Pragma("unroll")                                                        \
    for (int ks = 0; ks < 4; ++ks){                                          \
      float v[8];                                                            \
      *(float4*)&v[0] = *(const float4*)&T[colb * TS + ks * 32 + g * 8];     \
      *(float4*)&v[4] = *(const float4*)&T[colb * TS + ks * 32 + g * 8 + 4]; \
      split8(v, ah[ks], al[ks]);                                             \
    }

  // ---- stage 1: identity = lrelu(x @ W_in + b_in) -> LDS
  RUN_STAGE(wh1, wl1);
  #pragma unroll
  for (int nt = 0; nt < 8; ++nt){
    const int col = nt * 16 + colb;
    const float bc = b_in[col];
    #pragma unroll
    for (int r = 0; r < 4; ++r)
      T[(g * 4 + r) * TS + col] = lrelu(acc[nt][r] + bc);
  }
  LOAD_FRAGS_FROM_LDS();

  // ---- stage 2: y = lrelu(identity @ Wo1_top + t[inv]) -> LDS
  int rid[4];
  #pragma unroll
  for (int r = 0; r < 4; ++r) rid[r] = inv[rbase + r];
  RUN_STAGE(wh2, wl2);
  #pragma unroll
  for (int nt = 0; nt < 8; ++nt){
    const int col = nt * 16 + colb;
    #pragma unroll
    for (int r = 0; r < 4; ++r){
      float o = acc[nt][r] + trow[(size_t)rid[r] * 128 + col];
      T[(g * 4 + r) * TS + col] = lrelu(o);
    }
  }
  LOAD_FRAGS_FROM_LDS();

  // ---- stage 3: z = y @ Wo2 + bo2 -> global
  RUN_STAGE(wh3, wl3);
  #pragma unroll
  for (int nt = 0; nt < 8; ++nt){
    const int col = nt * 16 + colb;
    const float bc = bo2[col];
    #pragma unroll
    for (int r = 0; r < 4; ++r)
      z[(size_t)(rbase + r) * 128 + col] = acc[nt][r] + bc;
  }
  #undef RUN_STAGE
  #undef LOAD_FRAGS_FROM_LDS
}

// ======== f32 row-tiled GEMM (kept for the small ND-row BN stages) ========
template<int K, int N, bool LRELU, bool STATS, bool PRESCALE,
         bool TWOIN, bool ROWADD, bool BIAS>
__global__ __launch_bounds__(256) void k_gemm(
    const float* __restrict__ A, const float* __restrict__ A2,
    const float* __restrict__ scale, const float* __restrict__ shift,
    const float* __restrict__ W, const float* __restrict__ bias,
    const float* __restrict__ rowtab, const int* __restrict__ rowidx,
    float* __restrict__ out, float* __restrict__ stats, int M)
{
  constexpr int BM = 64;
  constexpr int G  = N / 4;
  constexpr int TY = 256 / G;
  constexpr int R  = BM / TY;
  constexpr int KV = K / 4;

  __shared__ float At[K][BM + 4];
  __shared__ int   sidx[ROWADD ? BM : 1];
  __shared__ float red[STATS ? 2 * TY * N : 1];

  const int tid  = threadIdx.x;
  const int tx   = tid % G;
  const int ty   = tid / G;
  const int row0 = blockIdx.x * BM;

  for (int i = tid; i < BM * KV; i += 256){
    int r  = i / KV;
    int kc = (i % KV) * 4;
    int row = row0 + r;
    float4 v = make_float4(0.f, 0.f, 0.f, 0.f);
    if (row < M){
      v = *(const float4*)(A + (size_t)row * K + kc);
      if constexpr (TWOIN){
        float4 w = *(const float4*)(A2 + (size_t)row * K + kc);
        v.x += w.x; v.y += w.y; v.z += w.z; v.w += w.w;
      }
      if constexpr (PRESCALE){
        v.x = v.x * scale[kc + 0] + shift[kc + 0];
        v.y = v.y * scale[kc + 1] + shift[kc + 1];
        v.z = v.z * scale[kc + 2] + shift[kc + 2];
        v.w = v.w * scale[kc + 3] + shift[kc + 3];
      }
    }
    At[kc + 0][r] = v.x; At[kc + 1][r] = v.y;
    At[kc + 2][r] = v.z; At[kc + 3][r] = v.w;
  }
  if constexpr (ROWADD){
    for (int i = tid; i < BM; i += 256){
      int row = row0 + i;
      sidx[i] = row < M ? rowidx[row] : 0;
    }
  }
  __syncthreads();

  float acc[R][4];
  #pragma unroll
  for (int r = 0; r < R; ++r)
    for (int j = 0; j < 4; ++j) acc[r][j] = 0.f;

  #pragma unroll 4
  for (int k = 0; k < K; ++k){
    float4 w4 = *(const float4*)(W + (size_t)k * N + tx * 4);
    const float4* ap = (const float4*)&At[k][ty * R];
    #pragma unroll
    for (int rq = 0; rq < R / 4; ++rq){
      float4 a4 = ap[rq];
      float av[4] = {a4.x, a4.y, a4.z, a4.w};
      #pragma unroll
      for (int rr = 0; rr < 4; ++rr){
        int r = rq * 4 + rr;
        acc[r][0] += av[rr] * w4.x;
        acc[r][1] += av[rr] * w4.y;
        acc[r][2] += av[rr] * w4.z;
        acc[r][3] += av[rr] * w4.w;
      }
    }
  }

  float bx[4] = {0.f, 0.f, 0.f, 0.f};
  if constexpr (BIAS){
    float4 b = *(const float4*)(bias + tx * 4);
    bx[0] = b.x; bx[1] = b.y; bx[2] = b.z; bx[3] = b.w;
  }

  float ps[4] = {0.f,0.f,0.f,0.f}, pq[4] = {0.f,0.f,0.f,0.f};
  #pragma unroll
  for (int r = 0; r < R; ++r){
    int row = row0 + ty * R + r;
    if (row < M){
      float o[4];
      #pragma unroll
      for (int j = 0; j < 4; ++j) o[j] = acc[r][j] + bx[j];
      if constexpr (ROWADD){
        int d = sidx[ty * R + r];
        float4 tv = *(const float4*)(rowtab + (size_t)d * N + tx * 4);
        o[0] += tv.x; o[1] += tv.y; o[2] += tv.z; o[3] += tv.w;
      }
      if constexpr (LRELU){
        #pragma unroll
        for (int j = 0; j < 4; ++j) o[j] = lrelu(o[j]);
      }
      *(float4*)(out + (size_t)row * N + tx * 4) = make_float4(o[0], o[1], o[2], o[3]);
      if constexpr (STATS){
        #pragma unroll
        for (int j = 0; j < 4; ++j){ ps[j] += o[j]; pq[j] += o[j] * o[j]; }
      }
    }
  }

  if constexpr (STATS){
    #pragma unroll
    for (int j = 0; j < 4; ++j){
      red[(0 * TY + ty) * N + tx * 4 + j] = ps[j];
      red[(1 * TY + ty) * N + tx * 4 + j] = pq[j];
    }
    __syncthreads();
    for (int col = tid; col < N; col += 256){
      float s = 0.f, q = 0.f;
      #pragma unroll
      for (int t2 = 0; t2 < TY; ++t2){
        s += red[(0 * TY + t2) * N + col];
        q += red[(1 * TY + t2) * N + col];
      }
      atomicAdd(&stats[col], s);
      atomicAdd(&stats[N + col], q);
    }
  }
}

__global__ void k_bn(const float* __restrict__ stats, const float* __restrict__ g,
                     const float* __restrict__ beta, float* __restrict__ scale,
                     float* __restrict__ shift, float inv_n){
  int c = threadIdx.x;   // 64 threads
  float mean = stats[c] * inv_n;
  float var  = stats[64 + c] * inv_n - mean * mean;
  float sc   = g[c] * rsqrtf(var + 1e-5f);
  scale[c] = sc;
  shift[c] = beta[c] - mean * sc;
}

inline int cdiv(int a, int b){ return (a + b - 1) / b; }

} // namespace

extern "C" void kernel_launch(void* const* d_in, const int* in_sizes, int n_in,
                              void* d_out, int out_size, void* d_ws, size_t ws_size,
                              hipStream_t stream){
  const float* features = (const float*)d_in[0];
  const float* v_fea    = (const float*)d_in[1];
  const int*   inv      = (const int*)d_in[2];
  const int*   cil      = (const int*)d_in[3];
  const int*   cin      = (const int*)d_in[4];
  const float* W_in  = (const float*)d_in[5];
  const float* b_in  = (const float*)d_in[6];
  const float* W1    = (const float*)d_in[7];
  const float* b1    = (const float*)d_in[8];
  const float* g1    = (const float*)d_in[9];
  const float* beta1 = (const float*)d_in[10];
  const float* W2    = (const float*)d_in[11];
  const float* b2    = (const float*)d_in[12];
  const float* g2    = (const float*)d_in[13];
  const float* beta2 = (const float*)d_in[14];
  const float* W3    = (const float*)d_in[15];
  const float* b3    = (const float*)d_in[16];
  const float* Wo1   = (const float*)d_in[17];
  const float* bo1   = (const float*)d_in[18];
  const float* Wo2   = (const float*)d_in[19];
  const float* bo2   = (const float*)d_in[20];

  // ---- workspace layout ----
  float* ws = (float*)d_ws;
  float* ds_mean = ws;                               // ND*C (t aliases later)
  float* h1      = ds_mean + (size_t)ND * C;         // ND*64
  float* h2      = h1 + (size_t)ND * 64;             // ND*64
  float* stats   = h2 + (size_t)ND * 64;             // 512
  float* big     = stats + 512;                      // NV*C: hm -> z
  int*   ip      = (int*)(big + (size_t)NV * C);
  int*   histc   = ip;                  // NSEG  = [histp(NV2) | histd(ND)]
  int*   off     = histc + NSEG;        // NSEG+1
  int*   next    = off + NSEG + 1;      // NSEG
  int*   tsum    = next + NSEG;         // scan tiles (<=256)
  int*   pid     = tsum + 256;          // NPTS
  int*   vsrc    = pid + NPTS;          // NPTS
  int*   vid     = vsrc + NPTS;         // NV
  // packed weights (16B-aligned): [w][hi 16384 | lo 16384], w = Win,Wo1t,Wo1b,Wo2
  unsigned short* pw =
      (unsigned short*)((((uintptr_t)(vid + NV)) + 15) & ~(uintptr_t)15);
  unsigned short* Win_h  = pw;
  unsigned short* Win_l  = pw + 16384;
  unsigned short* Wo1t_h = pw + 32768;
  unsigned short* Wo1t_l = pw + 49152;
  unsigned short* Wo1b_h = pw + 65536;
  unsigned short* Wo1b_l = pw + 81920;
  unsigned short* Wo2_h  = pw + 98304;
  unsigned short* Wo2_l  = pw + 114688;

  float* t      = ds_mean;        // alias: ds_mean dead after step 2, t born step 5
  float* stats1 = stats;
  float* stats2 = stats + 128;
  float* scale1 = stats + 256;
  float* shift1 = stats + 320;
  float* scale2 = stats + 384;
  float* shift2 = stats + 448;

  const int NT = cdiv(NSEG, ST);   // 176 scan tiles

  hipMemsetAsync(histc, 0, (size_t)NSEG * sizeof(int), stream);
  hipMemsetAsync(stats, 0, 256 * sizeof(float), stream);

  // ---- pack all four 128x128 weights (one launch) ----
  k_pack4<<<32, 256, 0, stream>>>(W_in, Wo1, Wo1 + (size_t)C * C, Wo2, pw);

  // ---- build segment point-lists (counting sort, hierarchical scan) ----
  k_hist2<<<cdiv(TOTAL, 256), 256, 0, stream>>>(cin, inv, histc);
  k_tilesum<<<NT, 256, 0, stream>>>(histc, NSEG, tsum);
  k_scantiles<<<1, 256, 0, stream>>>(tsum, NT);
  k_scanwrite<<<NT, 256, 0, stream>>>(histc, tsum, NSEG, off, next);
  k_order2<<<cdiv(TOTAL, 256), 256, 0, stream>>>(cin, cil, inv, next, pid, vsrc, vid);

  // 1) ds_mean = segment_mean(features+v_fea, inv)
  k_segmean_ds<<<cdiv(ND, 4), 256, 0, stream>>>(features, v_fea, off, vid, ds_mean);

  // 2) h1 = lrelu(ds_mean @ W1 + b1), BN1 stats   (f32 path)
  k_gemm<128, 64, true, true, false, false, false, true>
      <<<cdiv(ND, 64), 256, 0, stream>>>(ds_mean, nullptr, nullptr, nullptr,
                                          W1, b1, nullptr, nullptr, h1, stats1, ND);
  k_bn<<<1, 64, 0, stream>>>(stats1, g1, beta1, scale1, shift1, 1.f / ND);

  // 3) h2 = lrelu(bn1(h1) @ W2 + b2), BN2 stats   (f32 path)
  k_gemm<64, 64, true, true, true, false, false, true>
      <<<cdiv(ND, 64), 256, 0, stream>>>(h1, nullptr, scale1, shift1,
                                          W2, b2, nullptr, nullptr, h2, stats2, ND);
  k_bn<<<1, 64, 0, stream>>>(stats2, g2, beta2, scale2, shift2, 1.f / ND);

  // 4) hm = lrelu(bn2(h2) @ W3 + b3) -> big       (f32 path)
  k_gemm<64, 128, true, false, true, false, false, true>
      <<<cdiv(ND, 64), 256, 0, stream>>>(h2, nullptr, scale2, shift2,
                                          W3, b3, nullptr, nullptr, big, nullptr, ND);

  // 5) t = hm @ Wo1_bot + bo1                     (MFMA; t aliases ds_mean)
  k_mgemm<false, false, false, true><<<cdiv(ND, 64), 256, 0, stream>>>(
      big, nullptr, Wo1b_h, Wo1b_l, bo1, nullptr, nullptr, t, ND);

  // 6-8) fused: z = (lrelu(lrelu(x@W_in+b_in)@Wo1_top + t[inv]))@Wo2 + bo2 -> big
  k_fused3<<<cdiv(NV, 64), 256, 0, stream>>>(
      features, v_fea, Win_h, Win_l, Wo1t_h, Wo1t_l, Wo2_h, Wo2_l,
      b_in, t, inv, bo2, big, NV);

  // 9) fused: per-segment mean of z rows -> broadcast to out point rows
  k_segmean_p<<<cdiv(NV2, 4), 256, 0, stream>>>(big, off, pid, vsrc, (float*)d_out);

  (void)in_sizes; (void)n_in; (void)out_size; (void)ws_size;
}